// Round 15
// baseline (126.121 us; speedup 1.0000x reference)
//
#include <hip/hip_runtime.h>

// VectorQuantizerEMA: N=16384, K=1024, D=256.
// Outputs (f32, concat): recons [N,D] | gamma [N,K] | new_centroids [K,D]
// R15: recompute fusion with HAND-SPECIALIZED kernels (no templates; R10's
// 114us/instance was the rule-#19 co-compiled-template spill cliff).
//   gemm_stats: R7 gemm body -> per-(row,64col) stats {min,expsum,argmin}.
//   merge:      per-row m / 1/sum / idx (no atomics).
//   gemm_gamma: R7 gemm body -> writes normalized gamma directly.
//   dw_scan / reduce_fin / recons_fill: R14 verbatim. dist never hits HBM.

#define DECAY 0.95f
#define OMD   0.05f
#define EPSV  1e-5f

using i32x4  = __attribute__((ext_vector_type(4))) int;
using i32x16 = __attribute__((ext_vector_type(16))) int;

typedef __attribute__((address_space(3))) unsigned int       lds_uint;
typedef const __attribute__((address_space(1))) unsigned int glb_uint;

__device__ __forceinline__ void gload16(const void* g, const void* l) {
  __builtin_amdgcn_global_load_lds((glb_uint*)(unsigned long long)g,
                                   (lds_uint*)(unsigned int)(unsigned long long)l,
                                   16, 0, 0);
}

// ---------------------------------------------------------------- prep
__global__ __launch_bounds__(256) void prep(const float* __restrict__ z,
                                            const float* __restrict__ cent,
                                            const float* __restrict__ ema_cs,
                                            signed char* __restrict__ z8,
                                            signed char* __restrict__ c8,
                                            float* __restrict__ sz,
                                            float* __restrict__ sc,
                                            float* __restrict__ csq,
                                            float* __restrict__ S) {
  const int bid = blockIdx.x;
  const int t   = threadIdx.x;
  if (bid < 2176) {
    const bool isz = bid < 2048;
    const float* src = isz ? z : cent;
    const int rb = isz ? bid : (bid - 2048);
    const int r  = rb * 8 + (t >> 5);
    const int d0 = (t & 31) * 8;
    const float4 a = *(const float4*)&src[(size_t)r * 256 + d0];
    const float4 b = *(const float4*)&src[(size_t)r * 256 + d0 + 4];
    float f[8] = {a.x, a.y, a.z, a.w, b.x, b.y, b.z, b.w};
    float am = 0.f, ssq = 0.f;
#pragma unroll
    for (int j = 0; j < 8; ++j) { am = fmaxf(am, fabsf(f[j])); ssq += f[j] * f[j]; }
#pragma unroll
    for (int off = 16; off; off >>= 1) {
      am  = fmaxf(am, __shfl_down(am, off, 32));
      ssq += __shfl_down(ssq, off, 32);
    }
    am = __shfl(am, 0, 32);
    const float s  = fmaxf(am, 1e-6f) * (1.0f / 127.0f);
    const float rs = 1.0f / s;
    union { signed char c[8]; uint2 u; } H, L;
#pragma unroll
    for (int j = 0; j < 8; ++j) {
      float q = rintf(f[j] * rs);
      q = fminf(fmaxf(q, -127.f), 127.f);
      H.c[j] = (signed char)(int)q;
      float res = f[j] - q * s;
      float lq = rintf(res * rs * 256.0f);
      lq = fminf(fmaxf(lq, -127.f), 127.f);
      L.c[j] = (signed char)(int)lq;
    }
    signed char* dst = (isz ? z8 : c8) + (size_t)r * 512 + (d0 >> 6) * 128 + (d0 & 63);
    *(uint2*)dst        = H.u;
    *(uint2*)(dst + 64) = L.u;
    if ((t & 31) == 0) {
      if (isz) sz[r] = s;
      else { sc[r] = s; csq[r] = ssq; }
    }
  } else {
    float s = ema_cs[t] + ema_cs[t + 256] + ema_cs[t + 512] + ema_cs[t + 768];
#pragma unroll
    for (int off = 32; off; off >>= 1) s += __shfl_down(s, off);
    __shared__ float wsum[4];
    if ((t & 63) == 0) wsum[t >> 6] = s;
    __syncthreads();
    if (t == 0) S[0] = wsum[0] + wsum[1] + wsum[2] + wsum[3];
  }
}

// ---------------------------------------------------------------- gemm_stats
// R7 gemm body; epilogue writes per-(row, 64-col-block) {min, expsum, argmin}.
__global__ __launch_bounds__(256, 2) void gemm_stats(
    const signed char* __restrict__ z8, const signed char* __restrict__ c8,
    const float* __restrict__ sz, const float* __restrict__ sc,
    const float* __restrict__ csq,
    float* __restrict__ sm, float* __restrict__ se, int* __restrict__ si) {
  __shared__ signed char lds[2][128 * 128];

  const int tid  = threadIdx.x;
  const int lane = tid & 63;
  const int w    = tid >> 6;
  const int hi   = lane >> 5, l31 = lane & 31;

  const int bid = blockIdx.x;
  const int lin = (bid & 7) * 128 + (bid >> 3);
  const int m0  = (lin >> 3) * 128;
  const int n0  = (lin & 7) * 128;

  const int wm0 = (w >> 1) * 64;
  const int wn0 = (w & 1) * 64;
  const int wc  = w & 1;

  i32x16 accA[2][2], accB[2][2];
#pragma unroll
  for (int i = 0; i < 2; ++i)
#pragma unroll
    for (int j = 0; j < 2; ++j) { accA[i][j] = (i32x16)(0); accB[i][j] = (i32x16)(0); }

  const int srow = lane >> 3;
  const int scb  = lane & 7;

  for (int kk = 0; kk < 4; ++kk) {
    __syncthreads();
#pragma unroll
    for (int j = 0; j < 4; ++j) {
      const int r0    = w * 32 + j * 8;
      const int row   = r0 + srow;
      const int chunk = scb ^ (row & 7);
      gload16(z8 + (size_t)(m0 + row) * 512 + kk * 128 + chunk * 16, &lds[0][r0 * 128]);
      gload16(c8 + (size_t)(n0 + row) * 512 + kk * 128 + chunk * 16, &lds[1][r0 * 128]);
    }
    __syncthreads();
#pragma unroll
    for (int s = 0; s < 2; ++s) {
      i32x4 ah[2], al[2], bh[2], bl[2];
      const int kc = s * 2 + hi;
#pragma unroll
      for (int fi = 0; fi < 2; ++fi) {
        const int ra = wm0 + fi * 32 + l31;
        ah[fi] = *(const i32x4*)&lds[0][ra * 128 + ((kc)     ^ (ra & 7)) * 16];
        al[fi] = *(const i32x4*)&lds[0][ra * 128 + ((kc + 4) ^ (ra & 7)) * 16];
        const int rb = wn0 + fi * 32 + l31;
        bh[fi] = *(const i32x4*)&lds[1][rb * 128 + ((kc)     ^ (rb & 7)) * 16];
        bl[fi] = *(const i32x4*)&lds[1][rb * 128 + ((kc + 4) ^ (rb & 7)) * 16];
      }
#pragma unroll
      for (int i = 0; i < 2; ++i)
#pragma unroll
        for (int j = 0; j < 2; ++j) {
          accA[i][j] = __builtin_amdgcn_mfma_i32_32x32x32_i8(ah[i], bh[j], accA[i][j], 0, 0, 0);
          accB[i][j] = __builtin_amdgcn_mfma_i32_32x32x32_i8(ah[i], bl[j], accB[i][j], 0, 0, 0);
          accB[i][j] = __builtin_amdgcn_mfma_i32_32x32x32_i8(al[i], bh[j], accB[i][j], 0, 0, 0);
        }
    }
  }

  const int colb = n0 + wn0 + l31;
  const float sc0 = sc[colb],      cq0 = csq[colb];
  const float sc1 = sc[colb + 32], cq1 = csq[colb + 32];
  const int cb16 = (lin & 7) * 2 + wc;

#pragma unroll
  for (int i = 0; i < 2; ++i) {
#pragma unroll
    for (int reg = 0; reg < 16; ++reg) {
      const int lr = wm0 + i * 32 + (reg & 3) + 8 * (reg >> 2) + 4 * hi;
      const float szr = sz[m0 + lr];
      const float d0 = (float)accA[i][0][reg] + (float)accB[i][0][reg] * (1.0f / 256.0f);
      const float d1 = (float)accA[i][1][reg] + (float)accB[i][1][reg] * (1.0f / 256.0f);
      const float s0 = cq0 - 2.0f * szr * sc0 * d0;
      const float s1 = cq1 - 2.0f * szr * sc1 * d1;
      float mv; int mi;
      if (s1 < s0) { mv = s1; mi = colb + 32; } else { mv = s0; mi = colb; }
#pragma unroll
      for (int off = 16; off; off >>= 1) {
        const float ov = __shfl_xor(mv, off);
        const int   oi = __shfl_xor(mi, off);
        if (ov < mv || (ov == mv && oi < mi)) { mv = ov; mi = oi; }
      }
      float e = __expf(-5.0f * (s0 - mv)) + __expf(-5.0f * (s1 - mv));
#pragma unroll
      for (int off = 16; off; off >>= 1) e += __shfl_xor(e, off);
      if (l31 == 0) {
        const int gr = cb16 * 16384 + m0 + lr;
        sm[gr] = mv; se[gr] = e; si[gr] = mi;
      }
    }
  }
}

// ---------------------------------------------------------------- gemm_gamma
// R7 gemm body; epilogue writes gamma = exp(-5*(s-m))*inv directly.
__global__ __launch_bounds__(256, 2) void gemm_gamma(
    const signed char* __restrict__ z8, const signed char* __restrict__ c8,
    const float* __restrict__ sz, const float* __restrict__ sc,
    const float* __restrict__ csq,
    const float* __restrict__ fM, const float* __restrict__ fInv,
    float* __restrict__ gamma) {
  __shared__ signed char lds[2][128 * 128];
  __shared__ float fMl[128], fIl[128];

  const int tid  = threadIdx.x;
  const int lane = tid & 63;
  const int w    = tid >> 6;
  const int hi   = lane >> 5, l31 = lane & 31;

  const int bid = blockIdx.x;
  const int lin = (bid & 7) * 128 + (bid >> 3);
  const int m0  = (lin >> 3) * 128;
  const int n0  = (lin & 7) * 128;

  const int wm0 = (w >> 1) * 64;
  const int wn0 = (w & 1) * 64;

  if (tid < 128) { fMl[tid] = fM[m0 + tid]; fIl[tid] = fInv[m0 + tid]; }

  i32x16 accA[2][2], accB[2][2];
#pragma unroll
  for (int i = 0; i < 2; ++i)
#pragma unroll
    for (int j = 0; j < 2; ++j) { accA[i][j] = (i32x16)(0); accB[i][j] = (i32x16)(0); }

  const int srow = lane >> 3;
  const int scb  = lane & 7;

  for (int kk = 0; kk < 4; ++kk) {
    __syncthreads();
#pragma unroll
    for (int j = 0; j < 4; ++j) {
      const int r0    = w * 32 + j * 8;
      const int row   = r0 + srow;
      const int chunk = scb ^ (row & 7);
      gload16(z8 + (size_t)(m0 + row) * 512 + kk * 128 + chunk * 16, &lds[0][r0 * 128]);
      gload16(c8 + (size_t)(n0 + row) * 512 + kk * 128 + chunk * 16, &lds[1][r0 * 128]);
    }
    __syncthreads();
#pragma unroll
    for (int s = 0; s < 2; ++s) {
      i32x4 ah[2], al[2], bh[2], bl[2];
      const int kc = s * 2 + hi;
#pragma unroll
      for (int fi = 0; fi < 2; ++fi) {
        const int ra = wm0 + fi * 32 + l31;
        ah[fi] = *(const i32x4*)&lds[0][ra * 128 + ((kc)     ^ (ra & 7)) * 16];
        al[fi] = *(const i32x4*)&lds[0][ra * 128 + ((kc + 4) ^ (ra & 7)) * 16];
        const int rb = wn0 + fi * 32 + l31;
        bh[fi] = *(const i32x4*)&lds[1][rb * 128 + ((kc)     ^ (rb & 7)) * 16];
        bl[fi] = *(const i32x4*)&lds[1][rb * 128 + ((kc + 4) ^ (rb & 7)) * 16];
      }
#pragma unroll
      for (int i = 0; i < 2; ++i)
#pragma unroll
        for (int j = 0; j < 2; ++j) {
          accA[i][j] = __builtin_amdgcn_mfma_i32_32x32x32_i8(ah[i], bh[j], accA[i][j], 0, 0, 0);
          accB[i][j] = __builtin_amdgcn_mfma_i32_32x32x32_i8(ah[i], bl[j], accB[i][j], 0, 0, 0);
          accB[i][j] = __builtin_amdgcn_mfma_i32_32x32x32_i8(al[i], bh[j], accB[i][j], 0, 0, 0);
        }
    }
  }

  const int colb = n0 + wn0 + l31;
  const float sc0 = sc[colb],      cq0 = csq[colb];
  const float sc1 = sc[colb + 32], cq1 = csq[colb + 32];

#pragma unroll
  for (int i = 0; i < 2; ++i) {
#pragma unroll
    for (int reg = 0; reg < 16; ++reg) {
      const int lr = wm0 + i * 32 + (reg & 3) + 8 * (reg >> 2) + 4 * hi;
      const float szr = sz[m0 + lr];
      const float d0 = (float)accA[i][0][reg] + (float)accB[i][0][reg] * (1.0f / 256.0f);
      const float d1 = (float)accA[i][1][reg] + (float)accB[i][1][reg] * (1.0f / 256.0f);
      const float s0 = cq0 - 2.0f * szr * sc0 * d0;
      const float s1 = cq1 - 2.0f * szr * sc1 * d1;
      const float m = fMl[lr], inv = fIl[lr];
      float* gp = &gamma[(size_t)(m0 + lr) * 1024];
      gp[colb]      = __expf(-5.0f * (s0 - m)) * inv;
      gp[colb + 32] = __expf(-5.0f * (s1 - m)) * inv;
    }
  }
}

// ---------------------------------------------------------------- merge (no atomics)
__global__ __launch_bounds__(256) void merge_stats(const float* __restrict__ sm,
                                                   const float* __restrict__ se,
                                                   const int* __restrict__ si,
                                                   float* __restrict__ fM,
                                                   float* __restrict__ fInv,
                                                   int* __restrict__ fIdx) {
  const int r = blockIdx.x * 256 + threadIdx.x;
  float m = sm[r]; int mi = si[r];
#pragma unroll
  for (int cb = 1; cb < 16; ++cb) {
    const float mt = sm[cb * 16384 + r];
    const int   it = si[cb * 16384 + r];
    if (mt < m || (mt == m && it < mi)) { m = mt; mi = it; }
  }
  float sum = 0.f;
#pragma unroll
  for (int cb = 0; cb < 16; ++cb)
    sum += se[cb * 16384 + r] * __expf(-5.0f * (sm[cb * 16384 + r] - m));
  fM[r] = m; fInv[r] = 1.0f / sum; fIdx[r] = mi;
}

// ---------------------------------------------------------------- dw_scan (R14)
__global__ __launch_bounds__(512) void dw_scan(const float* __restrict__ z,
                                               const int* __restrict__ fIdx,
                                               float* __restrict__ dwp,
                                               int* __restrict__ cntp) {
  __shared__ float part[8][256];
  __shared__ int scnt[8];
  const int k    = blockIdx.x >> 2;
  const int s    = blockIdx.x & 3;
  const int ww   = threadIdx.x >> 6;
  const int lane = threadIdx.x & 63;

  float4 acc0 = {0.f, 0.f, 0.f, 0.f};
  float4 acc1 = {0.f, 0.f, 0.f, 0.f};
  int cnt = 0;
  const int base = s * 4096 + ww * 512;
  for (int c = 0; c < 512; c += 256) {
    const int4 fi = *(const int4*)&fIdx[base + c + lane * 4];
    unsigned long long m[4];
    m[0] = __ballot(fi.x == k);
    m[1] = __ballot(fi.y == k);
    m[2] = __ballot(fi.z == k);
    m[3] = __ballot(fi.w == k);
    cnt += __popcll(m[0]) + __popcll(m[1]) + __popcll(m[2]) + __popcll(m[3]);
#pragma unroll
    for (int q = 0; q < 4; q += 2) {
      unsigned long long ma = m[q], mb = m[q + 1];
      while (ma | mb) {
        if (ma) {
          const int b = __builtin_ctzll(ma); ma &= ma - 1;
          const int rr = base + c + b * 4 + q;
          const float4 zv = *(const float4*)&z[(size_t)rr * 256 + lane * 4];
          acc0.x += zv.x; acc0.y += zv.y; acc0.z += zv.z; acc0.w += zv.w;
        }
        if (mb) {
          const int b = __builtin_ctzll(mb); mb &= mb - 1;
          const int rr = base + c + b * 4 + q + 1;
          const float4 zv = *(const float4*)&z[(size_t)rr * 256 + lane * 4];
          acc1.x += zv.x; acc1.y += zv.y; acc1.z += zv.z; acc1.w += zv.w;
        }
      }
    }
  }
  acc0.x += acc1.x; acc0.y += acc1.y; acc0.z += acc1.z; acc0.w += acc1.w;
  *(float4*)&part[ww][lane * 4] = acc0;
  if (lane == 0) scnt[ww] = cnt;
  __syncthreads();
  if (ww == 0) {
    float4 tot = {0.f, 0.f, 0.f, 0.f};
    int c = 0;
#pragma unroll
    for (int e = 0; e < 8; ++e) {
      const float4 p = *(const float4*)&part[e][lane * 4];
      tot.x += p.x; tot.y += p.y; tot.z += p.z; tot.w += p.w;
      c += scnt[e];
    }
    *(float4*)&dwp[(size_t)blockIdx.x * 256 + lane * 4] = tot;
    if (lane == 0) cntp[blockIdx.x] = c;
  }
}

// ---------------------------------------------------------------- reduce_fin (R14)
__global__ __launch_bounds__(256) void reduce_fin(const float* __restrict__ dwp,
                                                  const int* __restrict__ cntp,
                                                  const float* __restrict__ ema_w,
                                                  const float* __restrict__ ema_cs,
                                                  const float* __restrict__ S,
                                                  float* __restrict__ outc,
                                                  float fN) {
  const int k = blockIdx.x;
  const int t = threadIdx.x;
  const size_t b0 = (size_t)k * 4 * 256 + t;
  const float dsum = (dwp[b0] + dwp[b0 + 256]) + (dwp[b0 + 512] + dwp[b0 + 768]);
  const int   c    = (cntp[k * 4] + cntp[k * 4 + 1]) + (cntp[k * 4 + 2] + cntp[k * 4 + 3]);
  const float n   = DECAY * S[0] + OMD * fN;
  const float v   = DECAY * ema_cs[k] + OMD * (float)c;
  const float ncs = (v + EPSV) / (n + 1024.0f * EPSV) * n;
  const size_t i  = (size_t)k * 256 + t;
  outc[i] = (DECAY * ema_w[i] + OMD * dsum) / ncs;
}

// ---------------------------------------------------------------- recons_fill (R14)
__global__ __launch_bounds__(256) void recons_fill(const float* __restrict__ cent,
                                                   const int* __restrict__ fIdx,
                                                   float* __restrict__ recons) {
  const int r    = blockIdx.x * 4 + (threadIdx.x >> 6);
  const int lane = threadIdx.x & 63;
  const int idx  = fIdx[r];
  *(float4*)&recons[(size_t)r * 256 + lane * 4] =
      *(const float4*)&cent[(size_t)idx * 256 + lane * 4];
}

// ---------------------------------------------------------------- launch
extern "C" void kernel_launch(void* const* d_in, const int* in_sizes, int n_in,
                              void* d_out, int out_size, void* d_ws, size_t ws_size,
                              hipStream_t stream) {
  const float* z      = (const float*)d_in[0];
  const float* cent   = (const float*)d_in[1];
  const float* ema_w  = (const float*)d_in[2];
  const float* ema_cs = (const float*)d_in[3];

  const int K = in_sizes[3];            // 1024
  const int D = in_sizes[1] / K;        // 256
  const int N = in_sizes[0] / D;        // 16384

  float* out    = (float*)d_out;
  float* recons = out;                              // [N,D] = 16 MB
  float* gamma  = out + (size_t)N * D;              // [N,K]
  float* outc   = gamma + (size_t)N * K;            // [K,D] = 1 MB

  // recons region scratch (all dead before recons_fill writes recons):
  signed char* z8 = (signed char*)recons;                          // [0, 8MB)
  float* sm  = (float*)((char*)recons + ((size_t)8 << 20));        // [8, 9MB)
  float* se  = (float*)((char*)recons + ((size_t)9 << 20));        // [9, 10MB)
  int*   si  = (int*)  ((char*)recons + ((size_t)10 << 20));       // [10, 11MB)
  float* dwp = (float*)((char*)recons + ((size_t)11 << 20));       // [11, 15MB)
  int*  cntp = (int*)  ((char*)recons + ((size_t)15 << 20));       // 16 KB

  // outc region scratch (outc written last by reduce_fin):
  signed char* c8 = (signed char*)outc;             // 512 KB
  float* sz = (float*)((char*)outc + (size_t)K * 512);  // N floats
  float* sc = sz + N;                               // K floats

  float* csq  = (float*)d_ws;                       // [K]
  float* S    = csq + K;                            // [1]
  float* fM   = S + 1;                              // [N]
  float* fInv = fM + N;                             // [N]
  int*   fIdx = (int*)(fInv + N);                   // [N]  (ws ~196 KB)

  prep<<<2177, 256, 0, stream>>>(z, cent, ema_cs, z8, c8, sz, sc, csq, S);

  gemm_stats<<<(N / 128) * (K / 128), 256, 0, stream>>>(z8, c8, sz, sc, csq, sm, se, si);

  merge_stats<<<N / 256, 256, 0, stream>>>(sm, se, si, fM, fInv, fIdx);

  gemm_gamma<<<(N / 128) * (K / 128), 256, 0, stream>>>(z8, c8, sz, sc, csq, fM, fInv, gamma);

  dw_scan<<<K * 4, 512, 0, stream>>>(z, fIdx, dwp, cntp);

  reduce_fin<<<K, 256, 0, stream>>>(dwp, cntp, ema_w, ema_cs, S, outc, (float)N);

  recons_fill<<<N / 4, 256, 0, stream>>>(cent, fIdx, recons);
}